// Round 7
// baseline (167.902 us; speedup 1.0000x reference)
//
#include <hip/hip_runtime.h>

// Guided blur (multichannel guided filter), B=8, C=Cp=3, H=W=512, k=5, eps=1e-4.
// SINGLE fused kernel, LDS-free, barrier-free, shuffle-free (DPP only), PACKED-FP32:
//   - wave = 4 x 16-lane segments; each segment: 16 raw cols, 12 valid a-cols, 8 output cols
//   - horizontal 5-taps via v_add + DPP row_shl:{1,2,4} (per-32-bit reg, VALU pipe)
//   - all bulk arithmetic in float2 ext-vectors so the backend emits v_pk_{fma,add,mul}_f32
//     (gfx950 packed FP32 = 2x scalar FP32 issue rate); channel pairing chosen so packed
//     operands stay aligned from stats -> solve -> stage-2 blur -> output combine
//   - stage 1: vertical 5-row roll of 21 stat channels -> hsum5 -> symmetric 3x3 solve -> a,b
//   - stage 2: hsum5 of a,b; vertical 5-row roll of those 12 -> combine with guidance -> out
//   - trips of 5 rows, template<int I>: all ring indices compile-time => SROA keeps rings in
//     VGPRs (round-5 lesson: runtime ring idx -> PromoteAlloca-to-LDS -> 40us LDS-pipe serial)
//   - SR=16 strips -> 4096 waves -> 4 waves/SIMD for latency hiding (round-6 was 2/SIMD)
// No d_ws usage.

namespace {

using f2 = __attribute__((ext_vector_type(2))) float;
__device__ __forceinline__ f2 mk(float a, float b) { f2 r; r.x = a; r.y = b; return r; }

constexpr int BN = 8;
constexpr int HH = 512;
constexpr int WW = 512;
constexpr int CSZ = HH * WW;
constexpr float GEPS = 1e-4f;
constexpr int SEGW = 8;             // output cols per 16-lane segment
constexpr int OUTW = 4 * SEGW;      // 32 output cols per wave
constexpr int SR   = 16;            // output rows per wave strip (reads SR+8 raw rows)

__device__ __forceinline__ int refl(int i, int n) {
    // jnp.pad reflect: -1 -> 1, -2 -> 2, n -> n-2, n+1 -> n-3
    if (i < 0) i = -i;
    if (i >= n) i = 2 * n - 2 - i;
    return i;
}

// DPP row_shl:N within each 16-lane row: lane u receives lane u+N (0 past row end).
template <int N>
__device__ __forceinline__ float shlN(float v) {
    return __builtin_bit_cast(float,
        __builtin_amdgcn_update_dpp(0, __builtin_bit_cast(int, v),
                                    0x100 + N, 0xF, 0xF, true));
}
// row-local lane u gets v[u]+v[u+1]+v[u+2]+v[u+3]+v[u+4]; valid for u <= 11.
__device__ __forceinline__ float hsum5(float v) {
    float t = v + shlN<1>(v);
    float q = t + shlN<2>(t);
    return q + shlN<4>(v);
}
__device__ __forceinline__ f2 hs2(f2 v) { return mk(hsum5(v.x), hsum5(v.y)); }

struct St {
    // stage-1 vertical window sums, packed:
    f2 Vm[3];    // (sI0,sI1) (sI2,sP0) (sP1,sP2)
    f2 Vq[3];    // (I0I0,I0I1) (I0I2,I1I1) (I1I2,I2I2)
    f2 Vc[4];    // (I0P0,I0P1) (I0P2,I1P0) (I1P1,I1P2) (I2P0,I2P1)
    float Vc4;   // I2P2
    f2 r1[5][3]; // ring of raw rows: (c0,c1)(c2,c3)(c4,c5)
    // stage-2:
    f2 V2[6];    // pairs: (a00,a01)(a10,a11)(a20,a21)(b0,b1)(a02,a12)(a22,b2)
    f2 r2[5][6];
};

struct Ctx {
    const float *g0, *g1, *g2, *p0, *p1, *p2;
    float *o0, *o1, *o2;
    int yb, xr, xs;
    bool wr;
};

// One raw row. rr = 5*t + I; ring slots use constexpr I ((5t+I)%5 == I).
template <int I, bool SUB1, bool SOLVE, bool V2SUB, bool OUT>
__device__ __forceinline__ void row(St& st, const Ctx& cx, int t) {
    const int rr = 5 * t + I;
    const int y = refl(cx.yb - 4 + rr, HH);
    const int off = y * WW + cx.xr;
    float c0 = cx.g0[off], c1 = cx.g1[off], c2 = cx.g2[off];
    float c3 = cx.p0[off], c4 = cx.p1[off], c5 = cx.p2[off];

    // guidance for this iter's output row — issued early to cover latency
    float go0 = 0.f, go1 = 0.f, go2 = 0.f;
    int oOff = 0;
    if constexpr (OUT) {
        oOff = (cx.yb + rr - 8) * WW + cx.xs;
        go0 = cx.g0[oOff]; go1 = cx.g1[oOff]; go2 = cx.g2[oOff];
    }

    // add current raw row (packed)
    st.Vm[0] += mk(c0, c1); st.Vm[1] += mk(c2, c3); st.Vm[2] += mk(c4, c5);
    st.Vq[0] += mk(c0, c0) * mk(c0, c1);
    st.Vq[1] += mk(c0, c1) * mk(c2, c1);
    st.Vq[2] += mk(c1, c2) * mk(c2, c2);
    st.Vc[0] += mk(c0, c0) * mk(c3, c4);
    st.Vc[1] += mk(c0, c1) * mk(c5, c3);
    st.Vc[2] += mk(c1, c1) * mk(c4, c5);
    st.Vc[3] += mk(c2, c2) * mk(c3, c4);
    st.Vc4   += c2 * c5;

    if constexpr (SUB1) {   // drop raw row rr-5 (same constexpr slot I)
        float o0 = st.r1[I][0].x, o1 = st.r1[I][0].y;
        float o2 = st.r1[I][1].x, o3 = st.r1[I][1].y;
        float o4 = st.r1[I][2].x, o5 = st.r1[I][2].y;
        st.Vm[0] -= mk(o0, o1); st.Vm[1] -= mk(o2, o3); st.Vm[2] -= mk(o4, o5);
        st.Vq[0] -= mk(o0, o0) * mk(o0, o1);
        st.Vq[1] -= mk(o0, o1) * mk(o2, o1);
        st.Vq[2] -= mk(o1, o2) * mk(o2, o2);
        st.Vc[0] -= mk(o0, o0) * mk(o3, o4);
        st.Vc[1] -= mk(o0, o1) * mk(o5, o3);
        st.Vc[2] -= mk(o1, o1) * mk(o4, o5);
        st.Vc[3] -= mk(o2, o2) * mk(o3, o4);
        st.Vc4   -= o2 * o5;
    }
    st.r1[I][0] = mk(c0, c1); st.r1[I][1] = mk(c2, c3); st.r1[I][2] = mk(c4, c5);

    if constexpr (SOLVE) {
        const float nrm = 0.04f;  // 1/25
        f2 Sm0 = hs2(st.Vm[0]) * nrm;   // (mI0, mI1)
        f2 Sm1 = hs2(st.Vm[1]) * nrm;   // (mI2, mP0)
        f2 Sm2 = hs2(st.Vm[2]) * nrm;   // (mP1, mP2)
        float mI0 = Sm0.x, mI1 = Sm0.y, mI2 = Sm1.x;
        float mP0 = Sm1.y, mP1 = Sm2.x, mP2 = Sm2.y;

        f2 vA = hs2(st.Vq[0]) * nrm - mk(mI0, mI0) * mk(mI0, mI1);  // (v00', v01)
        f2 vB = hs2(st.Vq[1]) * nrm - mk(mI0, mI1) * mk(mI2, mI1);  // (v02, v11')
        f2 vC = hs2(st.Vq[2]) * nrm - mk(mI1, mI2) * mk(mI2, mI2);  // (v12, v22')
        float v00 = vA.x + GEPS, v01 = vA.y, v02 = vB.x;
        float v11 = vB.y + GEPS, v12 = vC.x, v22 = vC.y + GEPS;

        f2 cA = hs2(st.Vc[0]) * nrm - mk(mI0, mI0) * mk(mP0, mP1);  // (c00,c01)
        f2 cB = hs2(st.Vc[1]) * nrm - mk(mI0, mI1) * mk(mP2, mP0);  // (c02,c10)
        f2 cC = hs2(st.Vc[2]) * nrm - mk(mI1, mI1) * mk(mP1, mP2);  // (c11,c12)
        f2 cD = hs2(st.Vc[3]) * nrm - mk(mI2, mI2) * mk(mP0, mP1);  // (c20,c21)
        float c22 = hsum5(st.Vc4) * nrm - mI2 * mP2;
        float c00 = cA.x, c01 = cA.y, c02 = cB.x, c10 = cB.y;
        float c11 = cC.x, c12 = cC.y, c20 = cD.x, c21 = cD.y;

        // symmetric 3x3 adjugate (packed pairs), A = PSD + eps*I => det > 0
        f2 iA = mk(v11, v02) * mk(v22, v12) - mk(v12, v01) * mk(v12, v22);  // (i00,i01)
        f2 iB = mk(v01, v00) * mk(v12, v22) - mk(v02, v02) * mk(v11, v02);  // (i02,i11)
        f2 iC = mk(v01, v00) * mk(v02, v11) - mk(v00, v01) * mk(v12, v01);  // (i12,i22)
        float i00 = iA.x, i01 = iA.y, i02 = iB.x, i11 = iB.y, i12 = iC.x, i22 = iC.y;
        float det = v00 * i00 + v01 * i01 + v02 * i02;
        float rd = __builtin_amdgcn_rcpf(det);

        f2 A0 = (i00 * mk(c00, c01) + i01 * mk(c10, c11) + i02 * mk(c20, c21)) * rd; // (a00,a01)
        f2 A1 = (i01 * mk(c00, c01) + i11 * mk(c10, c11) + i12 * mk(c20, c21)) * rd; // (a10,a11)
        f2 A2 = (i02 * mk(c00, c01) + i12 * mk(c10, c11) + i22 * mk(c20, c21)) * rd; // (a20,a21)
        f2 A3 = (mk(i00, i01) * c02 + mk(i01, i11) * c12 + mk(i02, i12) * c22) * rd; // (a02,a12)
        float a22 = (i02 * c02 + i12 * c12 + i22 * c22) * rd;

        f2 B01 = mk(mP0, mP1) - mI0 * A0 - mI1 * A1 - mI2 * A2;   // (b0,b1)
        float b2 = mP2 - (mI0 * A3.x + mI1 * A3.y + mI2 * a22);

        // stage 2: horizontal 5-tap now, vertical roll over a-rows
        f2 Hs[6];
        Hs[0] = hs2(A0); Hs[1] = hs2(A1); Hs[2] = hs2(A2);
        Hs[3] = hs2(B01); Hs[4] = hs2(A3); Hs[5] = hs2(mk(a22, b2));

#pragma unroll
        for (int k = 0; k < 6; ++k) {
            st.V2[k] += Hs[k];
            if constexpr (V2SUB) st.V2[k] -= st.r2[I][k];  // read old before overwrite
            st.r2[I][k] = Hs[k];
        }

        if constexpr (OUT) {
            const float n2 = 0.04f;
            f2 M0 = st.V2[0] * n2, M1 = st.V2[1] * n2, M2 = st.V2[2] * n2;
            f2 M3 = st.V2[3] * n2, M4 = st.V2[4] * n2, M5 = st.V2[5] * n2;
            // out_p = sum_c g_c * mean_a[c][p] + mean_b_p
            f2 o01 = go0 * M0 + go1 * M1 + go2 * M2 + M3;
            float o2v = go0 * M4.x + go1 * M4.y + go2 * M5.x + M5.y;
            if (cx.wr) {
                cx.o0[oOff] = o01.x;
                cx.o1[oOff] = o01.y;
                cx.o2[oOff] = o2v;
            }
        }
    }
}

__global__ __launch_bounds__(64, 3) void fused_kernel(
        const float* __restrict__ g, const float* __restrict__ p,
        float* __restrict__ out) {
    const int lane = threadIdx.x;       // 64 threads = 1 wave
    const int l    = lane & 15;
    const int seg  = lane >> 4;
    const int XO   = blockIdx.x * OUTW;
    const int bb   = blockIdx.z;

    const int xbase = XO + seg * SEGW - 2;          // a-col of row-local lane 0
    const int xrq   = xbase + l - 2;                // raw read col (pre-reflect)
    const int xo    = xbase + l + 2;                // output col (valid l < SEGW)

    Ctx cx;
    cx.g0 = g + (size_t)bb * 3 * CSZ; cx.g1 = cx.g0 + CSZ; cx.g2 = cx.g0 + 2 * CSZ;
    cx.p0 = p + (size_t)bb * 3 * CSZ; cx.p1 = cx.p0 + CSZ; cx.p2 = cx.p0 + 2 * CSZ;
    cx.o0 = out + (size_t)bb * 3 * CSZ; cx.o1 = cx.o0 + CSZ; cx.o2 = cx.o0 + 2 * CSZ;
    cx.yb = blockIdx.y * SR;
    cx.xr = refl(xrq, WW);
    cx.xs = (xo < WW) ? xo : (WW - 1);
    cx.wr = (l < SEGW);

    St st;
#pragma unroll
    for (int i = 0; i < 3; ++i) st.Vm[i] = mk(0.f, 0.f);
#pragma unroll
    for (int i = 0; i < 3; ++i) st.Vq[i] = mk(0.f, 0.f);
#pragma unroll
    for (int i = 0; i < 4; ++i) st.Vc[i] = mk(0.f, 0.f);
    st.Vc4 = 0.f;
#pragma unroll
    for (int i = 0; i < 6; ++i) st.V2[i] = mk(0.f, 0.f);

    // trip 0: rows 0..4 — accumulate; first solve at rr=4
    row<0, false, false, false, false>(st, cx, 0);
    row<1, false, false, false, false>(st, cx, 0);
    row<2, false, false, false, false>(st, cx, 0);
    row<3, false, false, false, false>(st, cx, 0);
    row<4, false, true,  false, false>(st, cx, 0);
    // trip 1: rows 5..9 — first outputs at rr=8,9; first V2-sub at rr=9
    row<0, true, true, false, false>(st, cx, 1);
    row<1, true, true, false, false>(st, cx, 1);
    row<2, true, true, false, false>(st, cx, 1);
    row<3, true, true, false, true >(st, cx, 1);
    row<4, true, true, true,  true >(st, cx, 1);
    // steady trips: rows 10..19
#pragma unroll 1
    for (int t = 2; t <= 3; ++t) {
        row<0, true, true, true, true>(st, cx, t);
        row<1, true, true, true, true>(st, cx, t);
        row<2, true, true, true, true>(st, cx, t);
        row<3, true, true, true, true>(st, cx, t);
        row<4, true, true, true, true>(st, cx, t);
    }
    // tail trip: rows 20..23 (last output row rr=23 -> yo=yb+15)
    row<0, true, true, true, true>(st, cx, 4);
    row<1, true, true, true, true>(st, cx, 4);
    row<2, true, true, true, true>(st, cx, 4);
    row<3, true, true, true, true>(st, cx, 4);
}

}  // namespace

extern "C" void kernel_launch(void* const* d_in, const int* in_sizes, int n_in,
                              void* d_out, int out_size, void* d_ws, size_t ws_size,
                              hipStream_t stream) {
    const float* g  = (const float*)d_in[0];   // guidance [8,3,512,512]
    const float* p  = (const float*)d_in[1];   // input    [8,3,512,512]
    float* out = (float*)d_out;                // [8,3,512,512]

    dim3 grid(WW / OUTW, HH / SR, BN);         // (16, 32, 8) = 4096 blocks
    dim3 block(64);                            // 1 wave per block

    hipLaunchKernelGGL(fused_kernel, grid, block, 0, stream, g, p, out);
}